// Round 10
// baseline (309.965 us; speedup 1.0000x reference)
//
#include <hip/hip_runtime.h>
#include <math.h>

#define E_DIM 1024
#define B_DIM 4
#define S_DIM 2048
#define H_DIM 16
#define D_HEAD 64
#define M_DIM (B_DIM * S_DIM)   // 8192
#define LOG2E 1.44269504f

typedef _Float16 half8 __attribute__((ext_vector_type(8)));
typedef _Float16 half4 __attribute__((ext_vector_type(4)));
typedef __fp16  fp16x2 __attribute__((ext_vector_type(2)));   // cvt_pkrtz return type
typedef float floatx4 __attribute__((ext_vector_type(4)));
#define MFMA_F16(a, b, c)  __builtin_amdgcn_mfma_f32_16x16x32_f16(a, b, c, 0, 0, 0)
#define MFMA16(a, b, c)    __builtin_amdgcn_mfma_f32_16x16x16f16(a, b, c, 0, 0, 0)

#if __has_builtin(__builtin_amdgcn_exp2f)
#define EXP2F(x) __builtin_amdgcn_exp2f(x)
#else
#define EXP2F(x) exp2f(x)
#endif

union H4 { fp16x2 h2[2]; half4 h4; };

// async global->LDS, 16B per lane; LDS dest = wave-uniform base + lane*16B
#define GLDS16(g, l)                                                          \
    __builtin_amdgcn_global_load_lds(                                         \
        (const __attribute__((address_space(1))) void*)(g),                   \
        (__attribute__((address_space(3))) void*)(l), 16, 0, 0)

// Split-K segment work list (40 segs per bh), sorted heavy-first.
// nseg(qb) = qb/4 + 1; seg covers chunks [8s, min(8s+8, 2qb+2)) of 64 keys.
__device__ const int SEG_QBLK[40] = {3,4,5,6,7,7,8,8,9,9,10,10,11,11,11,12,12,12,
                                     13,13,13,14,14,14,15,15,15,15,
                                     2,6,10,14, 1,5,9,13, 0,4,8,12};
__device__ const int SEG_SEG[40]  = {0,0,0,0,0,1,0,1,0,1,0,1,0,1,2,0,1,2,
                                     0,1,2,0,1,2,0,1,2,3,
                                     0,1,2,3, 0,1,2,3, 0,1,2,3};
__device__ const int SEG_BASE[16] = {0,1,2,3,4,6,8,10,12,15,18,21,24,28,32,36};

// ---------------- x: fp32 -> fp16 cast copy ----------------
__global__ __launch_bounds__(256) void cvt_x(
    const float* __restrict__ X, _Float16* __restrict__ Xh)
{
    size_t i = ((size_t)blockIdx.x * 256 + threadIdx.x) * 8;
    float4 a = *(const float4*)&X[i];
    float4 b = *(const float4*)&X[i + 4];
    half8 h = {(_Float16)a.x, (_Float16)a.y, (_Float16)a.z, (_Float16)a.w,
               (_Float16)b.x, (_Float16)b.y, (_Float16)b.z, (_Float16)b.w};
    *(half8*)&Xh[i] = h;
}

// ---------------- W: fp32 [k][n] -> fp16 [n][k] transpose ----------------
__global__ __launch_bounds__(256) void cvt_w(
    const float* __restrict__ W0, const float* __restrict__ W1,
    const float* __restrict__ W2, const float* __restrict__ W3,
    _Float16* __restrict__ T0, _Float16* __restrict__ T1,
    _Float16* __restrict__ T2, _Float16* __restrict__ T3)
{
    const int z = blockIdx.z;
    const float* W = (z == 0) ? W0 : (z == 1) ? W1 : (z == 2) ? W2 : W3;
    _Float16*   T  = (z == 0) ? T0 : (z == 1) ? T1 : (z == 2) ? T2 : T3;
    const int k0 = blockIdx.x * 64, n0 = blockIdx.y * 64;
    const int tid = threadIdx.x;
    __shared__ float t[64][65];
#pragma unroll
    for (int it = 0; it < 4; it++) {
        int r = it * 16 + (tid >> 4);
        int c = (tid & 15) * 4;
        float4 v = *(const float4*)&W[(size_t)(k0 + r) * E_DIM + n0 + c];
        t[r][c] = v.x; t[r][c + 1] = v.y; t[r][c + 2] = v.z; t[r][c + 3] = v.w;
    }
    __syncthreads();
#pragma unroll
    for (int it = 0; it < 2; it++) {
        int n = it * 32 + (tid >> 3);
        int kk = (tid & 7) * 8;
        half8 h;
#pragma unroll
        for (int j = 0; j < 8; j++) h[j] = (_Float16)t[kk + j][n];
        *(half8*)&T[(size_t)(n0 + n) * E_DIM + k0 + kk] = h;
    }
}

// ---------------- MFMA GEMM core (m97 structure) ----------------
#define GEMM_CORE(Aptr, Bptr)                                                 \
    const int tid = threadIdx.x;                                              \
    const int wave = tid >> 6, lane = tid & 63;                               \
    const int m16 = lane & 15, quad = lane >> 4;                              \
    const int wm = (wave >> 1) * 64, wn = (wave & 1) * 64;                    \
    const int m0 = blockIdx.x * 128, n0 = blockIdx.y * 128;                   \
    __shared__ _Float16 As[128 * 32];                                         \
    __shared__ _Float16 Bs[128 * 32];                                         \
    floatx4 acc[4][4];                                                        \
    const floatx4 zf = {0.f, 0.f, 0.f, 0.f};                                  \
    _Pragma("unroll") for (int i = 0; i < 4; i++)                             \
        _Pragma("unroll") for (int j = 0; j < 4; j++) acc[i][j] = zf;         \
    const int lrow = lane >> 2, lseg = lane & 3;                              \
    const _Float16* gA = (Aptr) + (size_t)(m0 + wave * 32 + lrow) * E_DIM + lseg * 8; \
    const _Float16* gB = (Bptr) + (size_t)(n0 + wave * 32 + lrow) * E_DIM + lseg * 8; \
    _Float16* lA = As + (wave * 32) * 32;                                     \
    _Float16* lB = Bs + (wave * 32) * 32;                                     \
    for (int k0 = 0; k0 < E_DIM; k0 += 32) {                                  \
        __syncthreads();                                                      \
        GLDS16(gA + k0, lA);                                                  \
        GLDS16(gA + 16 * E_DIM + k0, lA + 16 * 32);                           \
        GLDS16(gB + k0, lB);                                                  \
        GLDS16(gB + 16 * E_DIM + k0, lB + 16 * 32);                           \
        __syncthreads();                                                      \
        half8 af[4], bf[4];                                                   \
        _Pragma("unroll") for (int mt = 0; mt < 4; mt++)                      \
            af[mt] = *(const half8*)&As[(wm + mt * 16 + m16) * 32 + quad * 8];\
        _Pragma("unroll") for (int nt = 0; nt < 4; nt++)                      \
            bf[nt] = *(const half8*)&Bs[(wn + nt * 16 + m16) * 32 + quad * 8];\
        _Pragma("unroll") for (int mt = 0; mt < 4; mt++)                      \
            _Pragma("unroll") for (int nt = 0; nt < 4; nt++)                  \
                acc[mt][nt] = MFMA_F16(af[mt], bf[nt], acc[mt][nt]);          \
    }

// QKV projection epilogues write bank-swizzled blobs (16B block db ^ (row&7)):
//  Q blob: per (bh,qblk128): [q][d], pre-scaled by 0.125*log2(e) (exp2 softmax)
//  K blob: per (bh,kc64):    [k][d]
//  V blob: per (bh,kc64): V^T [d][k]
__global__ __launch_bounds__(256) void qkv_mfma(
    const _Float16* __restrict__ Xh,
    const _Float16* __restrict__ Tq, const float* __restrict__ bq,
    const _Float16* __restrict__ Tk, const float* __restrict__ bk,
    const _Float16* __restrict__ Tv, const float* __restrict__ bv,
    _Float16* __restrict__ Qo, _Float16* __restrict__ Ko, _Float16* __restrict__ Vo)
{
    const int z = blockIdx.z;
    const _Float16* Wt   = (z == 0) ? Tq : (z == 1) ? Tk : Tv;
    const float*    bias = (z == 0) ? bq : (z == 1) ? bk : bv;

    GEMM_CORE(Xh, Wt)

    if (z == 2) {
#pragma unroll
        for (int nt = 0; nt < 4; nt++) {
            int n = n0 + wn + nt * 16 + m16;
            int h = n >> 6, d = n & 63, d7 = n & 7;
            float bias_v = bias[n];
#pragma unroll
            for (int mt = 0; mt < 4; mt++) {
                int m_b = m0 + wm + mt * 16 + quad * 4;
                int b = m_b >> 11, s = m_b & 2047;
                int bh = b * H_DIM + h;
                size_t off = ((size_t)bh * 32 + (s >> 6)) * 4096
                           + (size_t)d * 64 + ((((s >> 3) & 7) ^ d7) * 8) + (s & 7);
                half4 hv;
#pragma unroll
                for (int r = 0; r < 4; r++) hv[r] = (_Float16)(acc[mt][nt][r] + bias_v);
                *(half4*)&Vo[off] = hv;
            }
        }
    } else {
        _Float16* Out = (z == 0) ? Qo : Ko;
        const float sc = (z == 0) ? 0.125f * LOG2E : 1.0f;
#pragma unroll
        for (int nt = 0; nt < 4; nt++) {
            int n = n0 + wn + nt * 16 + m16;
            int h = n >> 6;
            int db = (n >> 3) & 7, d7 = n & 7;
            float bias_v = bias[n];
#pragma unroll
            for (int mt = 0; mt < 4; mt++) {
#pragma unroll
                for (int r = 0; r < 4; r++) {
                    int m = m0 + wm + mt * 16 + quad * 4 + r;
                    int b = m >> 11, s = m & 2047;
                    int bh = b * H_DIM + h;
                    size_t off;
                    if (z == 0)
                        off = ((size_t)bh * 16 + (s >> 7)) * 8192
                            + (size_t)(s & 127) * 64 + ((db ^ (s & 7)) * 8) + d7;
                    else
                        off = ((size_t)bh * 32 + (s >> 6)) * 4096
                            + (size_t)(s & 63) * 64 + ((db ^ (s & 7)) * 8) + d7;
                    Out[off] = (_Float16)((acc[mt][nt][r] + bias_v) * sc);
                }
            }
        }
    }
}

// Output projection: A = O fp16 [M][E], writes fp32 [M][E]
__global__ __launch_bounds__(256) void out_mfma(
    const _Float16* __restrict__ Oh, const _Float16* __restrict__ To,
    const float* __restrict__ bias, float* __restrict__ Out)
{
    GEMM_CORE(Oh, To)

#pragma unroll
    for (int nt = 0; nt < 4; nt++) {
        int n = n0 + wn + nt * 16 + m16;
        float bias_v = bias[n];
#pragma unroll
        for (int mt = 0; mt < 4; mt++) {
#pragma unroll
            for (int r = 0; r < 4; r++) {
                int m = m0 + wm + mt * 16 + quad * 4 + r;
                Out[(size_t)m * E_DIM + n] = acc[mt][nt][r] + bias_v;
            }
        }
    }
}

// ---------------- Split-K MFMA causal flash attention ----------------
// S^T = K.Q^T via 16x16x32; P stays in registers (C-layout == B-operand of
// 16x16x16) and feeds O^T += V^T.P directly -- no LDS round trip.
// LDS: two 16KB regions [K 8KB | V 8KB]; Q staged in region 1, dead after
// fragment loads, then recycled as the second K/V buffer.
__global__ __launch_bounds__(256) void attn_mfma(
    const _Float16* __restrict__ Qb, const _Float16* __restrict__ Kb,
    const _Float16* __restrict__ Vb, _Float16* __restrict__ Opart,
    float* __restrict__ Mv, float* __restrict__ Lv, _Float16* __restrict__ O)
{
    const int bh = blockIdx.y;
    const int wid = blockIdx.x;
    const int qblk = SEG_QBLK[wid];
    const int seg  = SEG_SEG[wid];
    const int q0 = qblk * 128;
    const int c0 = seg * 8;
    const int c1 = min(c0 + 8, 2 * qblk + 2);
    const bool solo = (c0 == 0) && (c1 == 2 * qblk + 2);
    const int tid = threadIdx.x;
    const int wave = tid >> 6, lane = tid & 63;
    const int m16 = lane & 15, quad = lane >> 4;
    const int sw = m16 & 7;

    __shared__ _Float16 L[16384];   // [region0: K|V 8192][region1: K|V 8192] halves

    // stage Q (16 KB linear) into region 1; KV(c0) into region 0
    const _Float16* gQ = Qb + ((size_t)bh * 16 + qblk) * 8192;
#pragma unroll
    for (int t = 0; t < 4; t++) {
        int i = wave * 4 + t;
        GLDS16(gQ + i * 512 + lane * 8, L + 8192 + i * 512);
    }
    const _Float16* kp = Kb + (size_t)bh * 131072 + (size_t)c0 * 4096 + wave * 1024 + lane * 8;
    const _Float16* vp = Vb + (size_t)bh * 131072 + (size_t)c0 * 4096 + wave * 1024 + lane * 8;
    GLDS16(kp, L + wave * 1024);        GLDS16(kp + 512, L + wave * 1024 + 512);
    GLDS16(vp, L + 4096 + wave * 1024); GLDS16(vp + 512, L + 4096 + wave * 1024 + 512);
    __syncthreads();

    // loop-invariant Q fragments (B-operand of S^T) from region 1
    half8 qf[2][2];
#pragma unroll
    for (int mt = 0; mt < 2; mt++)
#pragma unroll
        for (int dh = 0; dh < 2; dh++)
            qf[mt][dh] = *(const half8*)&L[8192 + (wave * 32 + mt * 16 + m16) * 64
                                            + (((dh * 4 + quad) ^ sw) * 8)];
    __syncthreads();   // all waves' Q reads done -> region 1 reusable

    // loop-invariant LDS offsets (element units, relative to region base)
    int ko[4][2];      // K fragments (16x16x32 A-operand)
#pragma unroll
    for (int kt = 0; kt < 4; kt++) {
        ko[kt][0] = (kt * 16 + m16) * 64 + ((quad ^ sw) << 3);
        ko[kt][1] = (kt * 16 + m16) * 64 + (((quad + 4) ^ sw) << 3);
    }
    int vx[4], vrow[4];  // V fragments (16x16x16 A-operand): b64 at key quad*4
#pragma unroll
    for (int kt = 0; kt < 4; kt++)
        vx[kt] = (((kt * 2 + (quad >> 1)) ^ sw) << 3) + ((quad & 1) << 2);
#pragma unroll
    for (int dt = 0; dt < 4; dt++)
        vrow[dt] = 4096 + (dt * 16 + m16) * 64;

    float m_i[2] = {-INFINITY, -INFINITY}, l_i[2] = {0.f, 0.f};
    floatx4 acco[2][4];
    const floatx4 zf = {0.f, 0.f, 0.f, 0.f};
#pragma unroll
    for (int mt = 0; mt < 2; mt++)
#pragma unroll
        for (int dt = 0; dt < 4; dt++) acco[mt][dt] = zf;

    const int qmin = q0 + wave * 32;
    const int qmax = qmin + 31;

    for (int c = c0; c < c1; c++) {
        const int rbase = ((c - c0) & 1) * 8192;
        if (c + 1 < c1) {   // prefetch next chunk into the other region
            kp += 4096; vp += 4096;
            const int nb = rbase ^ 8192;
            GLDS16(kp, L + nb + wave * 1024);        GLDS16(kp + 512, L + nb + wave * 1024 + 512);
            GLDS16(vp, L + nb + 4096 + wave * 1024); GLDS16(vp + 512, L + nb + 4096 + wave * 1024 + 512);
        }
        const int k0 = c * 64;
        if (k0 <= qmax) {
            // ---- S^T = K.Q^T: 16 MFMAs (K=32) ----
            floatx4 sf[2][4];
#pragma unroll
            for (int kt = 0; kt < 4; kt++) {
                half8 kf0 = *(const half8*)&L[rbase + ko[kt][0]];
                half8 kf1 = *(const half8*)&L[rbase + ko[kt][1]];
#pragma unroll
                for (int mt = 0; mt < 2; mt++)
                    sf[mt][kt] = MFMA_F16(kf1, qf[mt][1], MFMA_F16(kf0, qf[mt][0], zf));
            }

            // ---- online softmax; P packed to registers (B-operand of 16x16x16) ----
            const bool full = (k0 + 63 <= qmin);
            half4 pk[2][4];
#pragma unroll
            for (int mt = 0; mt < 2; mt++) {
                const int qg = qmin + mt * 16 + m16;
                float p[4][4];
                float mx = -INFINITY;
#pragma unroll
                for (int kt = 0; kt < 4; kt++)
#pragma unroll
                    for (int r = 0; r < 4; r++) {
                        float v = sf[mt][kt][r];
                        if (!full) {
                            int key = k0 + kt * 16 + quad * 4 + r;
                            v = (key <= qg) ? v : -INFINITY;
                        }
                        p[kt][r] = v;
                        mx = fmaxf(mx, v);
                    }
                mx = fmaxf(mx, __shfl_xor(mx, 16));
                mx = fmaxf(mx, __shfl_xor(mx, 32));
                float mn = fmaxf(m_i[mt], mx);
                float alpha = EXP2F(m_i[mt] - mn);
                m_i[mt] = mn;
                float ls = 0.f;
#pragma unroll
                for (int kt = 0; kt < 4; kt++)
#pragma unroll
                    for (int r = 0; r < 4; r++) {
                        float e = EXP2F(p[kt][r] - mn);
                        p[kt][r] = e;
                        ls += e;
                    }
                ls += __shfl_xor(ls, 16);
                ls += __shfl_xor(ls, 32);
                l_i[mt] = l_i[mt] * alpha + ls;
#pragma unroll
                for (int dt = 0; dt < 4; dt++) acco[mt][dt] *= alpha;
#pragma unroll
                for (int kt = 0; kt < 4; kt++) {
                    H4 u;
                    u.h2[0] = __builtin_amdgcn_cvt_pkrtz(p[kt][0], p[kt][1]);
                    u.h2[1] = __builtin_amdgcn_cvt_pkrtz(p[kt][2], p[kt][3]);
                    pk[mt][kt] = u.h4;
                }
            }

            // ---- O^T += V^T.P: 32 MFMAs (K=16), P direct from registers ----
#pragma unroll
            for (int kt = 0; kt < 4; kt++) {
#pragma unroll
                for (int dt = 0; dt < 4; dt++) {
                    half4 vf = *(const half4*)&L[rbase + vrow[dt] + vx[kt]];
                    acco[0][dt] = MFMA16(vf, pk[0][kt], acco[0][dt]);
                    acco[1][dt] = MFMA16(vf, pk[1][kt], acco[1][dt]);
                }
            }
        }
        __syncthreads();   // reads of this region done; drains prefetch (covered)
    }

    if (solo) {
        // ---- single segment: normalize and write O fp16 [B,S,E] directly ----
        const int b = bh >> 4;
        const int h = bh & (H_DIM - 1);
#pragma unroll
        for (int mt = 0; mt < 2; mt++) {
            float inv = 1.f / l_i[mt];
            int q = qmin + mt * 16 + m16;
            _Float16* dst = O + (size_t)(b * S_DIM + q) * E_DIM + h * 64;
#pragma unroll
            for (int dt = 0; dt < 4; dt++) {
                H4 u;
                u.h2[0] = __builtin_amdgcn_cvt_pkrtz(acco[mt][dt][0] * inv, acco[mt][dt][1] * inv);
                u.h2[1] = __builtin_amdgcn_cvt_pkrtz(acco[mt][dt][2] * inv, acco[mt][dt][3] * inv);
                *(half4*)&dst[dt * 16 + quad * 4] = u.h4;
            }
        }
    } else {
        // ---- write unnormalized partial + (m,l) ----
        const size_t prow = ((size_t)bh * 40 + SEG_BASE[qblk] + seg) * 128;
#pragma unroll
        for (int mt = 0; mt < 2; mt++) {
            int lq = wave * 32 + mt * 16 + m16;
            if (quad == 0) {
                Mv[prow + lq] = m_i[mt];
                Lv[prow + lq] = l_i[mt];
            }
            _Float16* dst = Opart + (prow + lq) * 64;
#pragma unroll
            for (int dt = 0; dt < 4; dt++) {
                H4 u;
                u.h2[0] = __builtin_amdgcn_cvt_pkrtz(acco[mt][dt][0], acco[mt][dt][1]);
                u.h2[1] = __builtin_amdgcn_cvt_pkrtz(acco[mt][dt][2], acco[mt][dt][3]);
                *(half4*)&dst[dt * 16 + quad * 4] = u.h4;
            }
        }
    }
}

// ---------------- combine partials -> O fp16 [B,S,E] (qb >= 4 only) ----------------
__global__ __launch_bounds__(256) void attn_combine(
    const _Float16* __restrict__ Opart, const float* __restrict__ Mv,
    const float* __restrict__ Lv, _Float16* __restrict__ O)
{
    const int qb = blockIdx.x + 4, bh = blockIdx.y;
    const int nseg = (qb >> 2) + 1;
    const size_t pbase = ((size_t)bh * 40 + SEG_BASE[qb]) * 128;
    const int t = threadIdx.x;
    const int r = t >> 1, dh = (t & 1) * 32;

    float m_s[4], w[4];
    float M = -INFINITY;
    for (int s = 0; s < nseg; s++) {
        m_s[s] = Mv[pbase + s * 128 + r];
        M = fmaxf(M, m_s[s]);
    }
    float L = 0.f;
    for (int s = 0; s < nseg; s++) {
        w[s] = EXP2F(m_s[s] - M);
        L += Lv[pbase + s * 128 + r] * w[s];
    }
    const float invL = 1.f / L;

    const int b = bh >> 4, h = bh & (H_DIM - 1);
    const int q = qb * 128 + r;
    _Float16* dst = O + (size_t)(b * S_DIM + q) * E_DIM + h * 64 + dh;
#pragma unroll
    for (int d0 = 0; d0 < 32; d0 += 8) {
        float acc[8] = {0.f, 0.f, 0.f, 0.f, 0.f, 0.f, 0.f, 0.f};
        for (int s = 0; s < nseg; s++) {
            half8 v = *(const half8*)&Opart[(pbase + s * 128 + r) * 64 + dh + d0];
#pragma unroll
            for (int j = 0; j < 8; j++) acc[j] += w[s] * (float)v[j];
        }
        half8 o;
#pragma unroll
        for (int j = 0; j < 8; j++) o[j] = (_Float16)(acc[j] * invL);
        *(half8*)&dst[d0] = o;
    }
}

// ---------------- launch ----------------
extern "C" void kernel_launch(void* const* d_in, const int* in_sizes, int n_in,
                              void* d_out, int out_size, void* d_ws, size_t ws_size,
                              hipStream_t stream) {
    const float* x  = (const float*)d_in[0];
    const float* Wq = (const float*)d_in[1];
    const float* bq = (const float*)d_in[2];
    const float* Wk = (const float*)d_in[3];
    const float* bk = (const float*)d_in[4];
    const float* Wv = (const float*)d_in[5];
    const float* bv = (const float*)d_in[6];
    const float* Wo = (const float*)d_in[7];
    const float* bo = (const float*)d_in[8];

    const size_t SZ = (size_t)M_DIM * E_DIM;   // 8 Mi elements
    const size_t WZ = (size_t)E_DIM * E_DIM;
    _Float16* Xh = (_Float16*)d_ws;            // 16 MB (reused as Oh)
    _Float16* Tq = Xh + SZ;
    _Float16* Tk = Tq + WZ;
    _Float16* Tv = Tk + WZ;
    _Float16* To = Tv + WZ;
    _Float16* Qb = To + WZ;                    // swizzled blobs, 16 MB each
    _Float16* Kb = Qb + SZ;
    _Float16* Vb = Kb + SZ;
    _Float16* Opart = Vb + SZ;                 // 2560 * 8192 fp16 = 41.9 MB
    float* Mv = (float*)(Opart + (size_t)2560 * 8192);   // 2560*128 fp32
    float* Lv = Mv + 2560 * 128;
    _Float16* Oh = Xh;                         // alias: x dead after qkv_mfma

    cvt_x<<<dim3(M_DIM * E_DIM / 2048), 256, 0, stream>>>(x, Xh);
    cvt_w<<<dim3(16, 16, 4), 256, 0, stream>>>(Wq, Wk, Wv, Wo, Tq, Tk, Tv, To);

    qkv_mfma<<<dim3(M_DIM / 128, E_DIM / 128, 3), 256, 0, stream>>>(
        Xh, Tq, bq, Tk, bk, Tv, bv, Qb, Kb, Vb);

    attn_mfma<<<dim3(40, B_DIM * H_DIM), 256, 0, stream>>>(
        Qb, Kb, Vb, Opart, Mv, Lv, Oh);

    attn_combine<<<dim3(12, B_DIM * H_DIM), 256, 0, stream>>>(Opart, Mv, Lv, Oh);

    out_mfma<<<dim3(M_DIM / 128, E_DIM / 128), 256, 0, stream>>>(
        Oh, To, bo, (float*)d_out);
}